// Round 1
// baseline (749.735 us; speedup 1.0000x reference)
//
#include <hip/hip_runtime.h>
#include <hip/hip_bf16.h>

// Decoder: one-hot@Wx gather -> 64-step LSTM -> Bahdanau attention softmax.
// B=32, T=64, S=64, U=512, 4U=2048, VOCAB=65.
//
// Design (round 1):
//  - lstm_kernel: 32 persistent wgs (one per 16-unit slice of h, all batches),
//    Wh held in VGPRs as bf16 MFMA B-fragments (preloaded once). Per step:
//    z[32,64] = h[32,512] @ WhSlice (MFMA 16x16x32), gate update in fp32,
//    h broadcast via LLC-bypass (agent-scope relaxed atomics) + custom
//    monotonic-counter device barrier. c stays in LDS. dec history -> ws.
//  - proj_kernel: d1 = dec@W1+b1, e2 = enc@W2+b2 (bf16 out, MFMA).
//  - score_kernel: one wave per (b,t): score_s = sum_u tanh(d1+e2)*V,
//    in-wave softmax over S=64 lanes, transposed store [B,S,T].

#define NB 32
#define NT 64
#define NS 64
#define NU 512
#define N4U 2048
#define NV 65
#define NWG 32

typedef unsigned int u32;
typedef __bf16 bf16_t;
typedef bf16_t bf16x8 __attribute__((ext_vector_type(8)));
typedef float f32x4 __attribute__((ext_vector_type(4)));

__device__ __forceinline__ unsigned short f2bf(float f) {
  u32 u = __builtin_bit_cast(u32, f);
  u += 0x7fffu + ((u >> 16) & 1u);   // round-to-nearest-even
  return (unsigned short)(u >> 16);
}
__device__ __forceinline__ float bf2f(unsigned short s) {
  return __builtin_bit_cast(float, (u32)s << 16);
}
__device__ __forceinline__ float sigf(float x) { return 1.0f / (1.0f + __expf(-x)); }
__device__ __forceinline__ float tanhfast(float x) {
  float e = __expf(2.0f * x);
  return 1.0f - 2.0f / (e + 1.0f);   // exact at +-inf, ~1e-6 rel otherwise
}

// ---------------------------------------------------------------------------
// LSTM: grid = 32 wgs x 256 threads (4 waves: wm = batch-half, wn = col-half).
// wg g owns h units [g*16, g*16+16) => its 64 z-columns are
// j = gate*512 + g*16 + u  (gate-local update, no cross-wg gate traffic).
// ---------------------------------------------------------------------------
__global__ __launch_bounds__(256, 1)
void lstm_kernel(const int* __restrict__ labels,
                 const float* __restrict__ h0,
                 const float* __restrict__ c0,
                 const float* __restrict__ Wx,
                 const float* __restrict__ Wh,
                 const float* __restrict__ bias,
                 u32* __restrict__ hbuf,    // [2][32][256] bf16-pairs (LLC-bypass)
                 u32* __restrict__ dec_u,   // [32*64][256] bf16-pairs (plain)
                 u32* __restrict__ ctr)     // barrier counter (memset 0 per launch)
{
  __shared__ u32   h_lds[NB * 256];   // 32KB, bf16 pairs, XOR-swizzled rows
  __shared__ float z_buf[NB][65];     // padded: conflict-free gate reads
  __shared__ float c_lds[NB][16];
  __shared__ float wx_lds[NV][65];    // Wx slice + bias folded, padded

  const int tid  = threadIdx.x;
  const int g    = blockIdx.x;
  const int wave = tid >> 6, lane = tid & 63;
  const int wm   = wave >> 1, wn = wave & 1;
  const int l15  = lane & 15, l4 = lane >> 4;

  // Wx gather slice (+bias folded): wx_lds[v][c] = Wx[v][gate*512+g*16+u] + b[j]
  for (int i = tid; i < NV * 64; i += 256) {
    int v = i >> 6, c = i & 63;
    int j = (c >> 4) * NU + g * 16 + (c & 15);
    wx_lds[v][c] = Wx[v * N4U + j] + bias[j];
  }
  // c0 slice
  for (int i = tid; i < NB * 16; i += 256) {
    int r = i >> 4, u = i & 15;
    c_lds[r][u] = c0[r * NU + g * 16 + u];
  }
  // h0 -> LDS (bf16, swizzled: uint idx ^= (row&7)<<2  <=> byte ^= (row&7)<<4)
  for (int i = tid; i < NB * 256; i += 256) {
    int r = i >> 8, cu = i & 255;
    u32 pk = (u32)f2bf(h0[r * NU + cu * 2]) | ((u32)f2bf(h0[r * NU + cu * 2 + 1]) << 16);
    h_lds[i ^ ((r & 7) << 2)] = pk;
  }

  // Wh B-fragments -> VGPRs, once. frag(kt,nt): lane holds Wh[k][j],
  // k = kt*32 + (lane>>4)*8 + e, j = col(wn*32 + nt*16 + (lane&15)).
  bf16x8 bfrag[16][2];
#pragma unroll
  for (int kt = 0; kt < 16; ++kt) {
#pragma unroll
    for (int nt = 0; nt < 2; ++nt) {
      int c = wn * 32 + nt * 16 + l15;
      int j = (c >> 4) * NU + g * 16 + (c & 15);
      int kb = kt * 32 + l4 * 8;
      union { unsigned short us[8]; bf16x8 v; } bu;
#pragma unroll
      for (int e = 0; e < 8; ++e) bu.us[e] = f2bf(Wh[(kb + e) * N4U + j]);
      bfrag[kt][nt] = bu.v;
    }
  }

  const int bb = tid >> 3;          // batch handled in update phase
  const int u2 = (tid & 7) * 2;     // unit pair
  const int ci = g * 8 + (tid & 7); // uint col in [32][256] h layout

  for (int s = 0; s < NT; ++s) {
    __syncthreads();  // h_lds ready / z_buf free

    // z = h @ WhSlice
    f32x4 acc0 = {0.f, 0.f, 0.f, 0.f};
    f32x4 acc1 = {0.f, 0.f, 0.f, 0.f};
    const int arow = wm * 16 + l15;
#pragma unroll
    for (int kt = 0; kt < 16; ++kt) {
      int bo = (arow << 10) + (kt << 6) + (l4 << 4);
      bo ^= (arow & 7) << 4;
      bf16x8 a = *reinterpret_cast<const bf16x8*>(
          reinterpret_cast<const char*>(h_lds) + bo);
      acc0 = __builtin_amdgcn_mfma_f32_16x16x32_bf16(a, bfrag[kt][0], acc0, 0, 0, 0);
      acc1 = __builtin_amdgcn_mfma_f32_16x16x32_bf16(a, bfrag[kt][1], acc1, 0, 0, 0);
    }
#pragma unroll
    for (int ri = 0; ri < 4; ++ri) {
      z_buf[wm * 16 + l4 * 4 + ri][wn * 32 + l15]      = acc0[ri];
      z_buf[wm * 16 + l4 * 4 + ri][wn * 32 + 16 + l15] = acc1[ri];
    }
    __syncthreads();

    // gate update (each thread owns (bb, u2..u2+1))
    int lab = labels[bb * NT + s];
    float hv[2];
#pragma unroll
    for (int q = 0; q < 2; ++q) {
      int u = u2 + q;
      float zi = z_buf[bb][u]      + wx_lds[lab][u];
      float zf = z_buf[bb][16 + u] + wx_lds[lab][16 + u];
      float zg = z_buf[bb][32 + u] + wx_lds[lab][32 + u];
      float zo = z_buf[bb][48 + u] + wx_lds[lab][48 + u];
      float cc = sigf(zf) * c_lds[bb][u] + sigf(zi) * tanhfast(zg);
      c_lds[bb][u] = cc;
      hv[q] = sigf(zo) * tanhfast(cc);
    }
    u32 pk = (u32)f2bf(hv[0]) | ((u32)f2bf(hv[1]) << 16);
    dec_u[(bb * NT + s) * 256 + ci] = pk;  // history for attention (plain store)
    if (s == NT - 1) break;                // last h not needed cross-wg
    __hip_atomic_store(hbuf + (((s + 1) & 1) << 13) + bb * 256 + ci, pk,
                       __ATOMIC_RELAXED, __HIP_MEMORY_SCOPE_AGENT);

    // device barrier: all h stores at LLC before arrive; monotonic counter
    asm volatile("s_waitcnt vmcnt(0)" ::: "memory");
    __syncthreads();
    if (tid == 0) {
      __hip_atomic_fetch_add(ctr, 1u, __ATOMIC_RELAXED, __HIP_MEMORY_SCOPE_AGENT);
      u32 target = (u32)(s + 1) * NWG;
      int guard = 0;
      while (__hip_atomic_load(ctr, __ATOMIC_RELAXED, __HIP_MEMORY_SCOPE_AGENT) < target) {
        if (++guard > 1000000) break;  // anti-hang; breaks => visible absmax fail
        __builtin_amdgcn_s_sleep(1);
      }
    }
    __syncthreads();

    // reload full h (LLC-bypass loads), re-swizzle into LDS
    const u32* hb = hbuf + (((s + 1) & 1) << 13);
    for (int i = tid; i < NB * 256; i += 256) {
      int r = i >> 8;
      u32 pk2 = __hip_atomic_load(hb + i, __ATOMIC_RELAXED, __HIP_MEMORY_SCOPE_AGENT);
      h_lds[i ^ ((r & 7) << 2)] = pk2;
    }
    // loop-top __syncthreads separates these writes from next MFMA reads
  }
}

// ---------------------------------------------------------------------------
// proj: rows 0..2047 -> d1 = dec@W1+b1 ; rows 2048..4095 -> e2 = enc@W2+b2.
// One wave = 16 rows x 64 cols. grid 512 x 256.
// ---------------------------------------------------------------------------
__global__ __launch_bounds__(256, 1)
void proj_kernel(const u32* __restrict__ dec_u,
                 const float* __restrict__ enc,
                 const float* __restrict__ W1,
                 const float* __restrict__ b1,
                 const float* __restrict__ W2,
                 const float* __restrict__ b2,
                 unsigned short* __restrict__ d1_bf,
                 unsigned short* __restrict__ e2_bf)
{
  const int tid = threadIdx.x;
  const int wave = tid >> 6, lane = tid & 63;
  const int l15 = lane & 15, l4 = lane >> 4;
  const int w  = blockIdx.x * 4 + wave;   // 0..2047
  const int rt = w >> 3, cg = w & 7;
  const bool isdec = (rt < 128);
  const int r0 = (isdec ? rt : rt - 128) * 16;
  const float* Wm  = isdec ? W1 : W2;
  const float* bv_ = isdec ? b1 : b2;
  unsigned short* outp = isdec ? d1_bf : e2_bf;

  f32x4 acc[4] = {};
  const int arow = r0 + l15;
  for (int kt = 0; kt < 16; ++kt) {
    int k0 = kt * 32 + l4 * 8;
    bf16x8 a;
    if (isdec) {
      a = __builtin_bit_cast(bf16x8,
            *reinterpret_cast<const uint4*>(dec_u + arow * 256 + (k0 >> 1)));
    } else {
      const float* ep = enc + arow * NU + k0;
      union { unsigned short us[8]; bf16x8 v; } au;
#pragma unroll
      for (int e = 0; e < 8; ++e) au.us[e] = f2bf(ep[e]);
      a = au.v;
    }
#pragma unroll
    for (int nt = 0; nt < 4; ++nt) {
      int col = cg * 64 + nt * 16 + l15;
      union { unsigned short us[8]; bf16x8 v; } bu;
#pragma unroll
      for (int e = 0; e < 8; ++e) bu.us[e] = f2bf(Wm[(k0 + e) * NU + col]);
      acc[nt] = __builtin_amdgcn_mfma_f32_16x16x32_bf16(a, bu.v, acc[nt], 0, 0, 0);
    }
  }
#pragma unroll
  for (int nt = 0; nt < 4; ++nt) {
    int col = cg * 64 + nt * 16 + l15;
    float bc = bv_[col];
#pragma unroll
    for (int ri = 0; ri < 4; ++ri) {
      int row = r0 + l4 * 4 + ri;
      outp[row * NU + col] = f2bf(acc[nt][ri] + bc);
    }
  }
}

// ---------------------------------------------------------------------------
// score+softmax: one wave per (b,t). lane s holds score[b,t,s]; softmax over
// lanes; store transposed out[b][s][t]. bv is softmax-invariant (dropped).
// grid 512 x 256.
// ---------------------------------------------------------------------------
__global__ __launch_bounds__(256, 1)
void score_kernel(const unsigned short* __restrict__ d1_bf,
                  const unsigned short* __restrict__ e2_bf,
                  const float* __restrict__ V,
                  float* __restrict__ out)
{
  const int tid = threadIdx.x;
  const int wave = tid >> 6, lane = tid & 63;
  const int p = blockIdx.x * 4 + wave;   // 0..2047
  const int bb = p >> 6, t = p & 63;

  union { uint4 q; unsigned short us[8]; } dv;
  dv.q = *reinterpret_cast<const uint4*>(d1_bf + (bb * 64 + t) * NU + lane * 8);
  float d1f[8], Vf[8];
#pragma unroll
  for (int e = 0; e < 8; ++e) { d1f[e] = bf2f(dv.us[e]); Vf[e] = V[lane * 8 + e]; }

  float sc = 0.f;
  for (int s = 0; s < NS; ++s) {
    union { uint4 q; unsigned short us[8]; } ev;
    ev.q = *reinterpret_cast<const uint4*>(e2_bf + (bb * 64 + s) * NU + lane * 8);
    float part = 0.f;
#pragma unroll
    for (int e = 0; e < 8; ++e) part += tanhfast(d1f[e] + bf2f(ev.us[e])) * Vf[e];
#pragma unroll
    for (int o = 32; o > 0; o >>= 1) part += __shfl_xor(part, o);
    sc = (lane == s) ? part : sc;
  }
  float m = sc;
#pragma unroll
  for (int o = 32; o > 0; o >>= 1) m = fmaxf(m, __shfl_xor(m, o));
  float ex = __expf(sc - m);
  float sum = ex;
#pragma unroll
  for (int o = 32; o > 0; o >>= 1) sum += __shfl_xor(sum, o);
  out[(bb * 64 + lane) * 64 + t] = ex / sum;
}

// ---------------------------------------------------------------------------
extern "C" void kernel_launch(void* const* d_in, const int* in_sizes, int n_in,
                              void* d_out, int out_size, void* d_ws, size_t ws_size,
                              hipStream_t stream)
{
  (void)in_sizes; (void)n_in; (void)out_size;
  const int*   labels = (const int*)  d_in[0];
  const float* enc    = (const float*)d_in[1];
  const float* h0     = (const float*)d_in[2];
  const float* c0     = (const float*)d_in[3];
  const float* Wx     = (const float*)d_in[4];
  const float* Wh     = (const float*)d_in[5];
  const float* bias   = (const float*)d_in[6];
  const float* W1     = (const float*)d_in[7];
  const float* b1     = (const float*)d_in[8];
  const float* W2     = (const float*)d_in[9];
  const float* b2     = (const float*)d_in[10];
  const float* V      = (const float*)d_in[11];
  // d_in[12] = bv: additive scalar on all scores -> softmax-invariant.

  char* ws = (char*)d_ws;
  const size_t OFS_HBUF = 1024;                       // 64KB
  const size_t OFS_DEC  = 1u << 17;                   // 2MB
  const size_t OFS_D1   = OFS_DEC + (2u << 20);       // 2MB
  const size_t OFS_E2   = OFS_D1  + (2u << 20);       // 2MB
  if (ws_size < OFS_E2 + (2u << 20)) return;          // ~8.4MB needed

  u32* ctr   = (u32*)(ws);
  u32* hbuf  = (u32*)(ws + OFS_HBUF);
  u32* dec_u = (u32*)(ws + OFS_DEC);
  unsigned short* d1_bf = (unsigned short*)(ws + OFS_D1);
  unsigned short* e2_bf = (unsigned short*)(ws + OFS_E2);
  float* out = (float*)d_out;

  hipMemsetAsync(ctr, 0, 256, stream);
  lstm_kernel<<<dim3(NWG), dim3(256), 0, stream>>>(labels, h0, c0, Wx, Wh, bias,
                                                   hbuf, dec_u, ctr);
  proj_kernel<<<dim3(512), dim3(256), 0, stream>>>(dec_u, enc, W1, b1, W2, b2,
                                                   d1_bf, e2_bf);
  score_kernel<<<dim3(512), dim3(256), 0, stream>>>(d1_bf, e2_bf, V, out);
}

// Round 2
// 739.908 us; speedup vs baseline: 1.0133x; 1.0133x over previous
//
#include <hip/hip_runtime.h>
#include <hip/hip_bf16.h>

// Decoder: one-hot@Wx gather -> 64-step LSTM -> Bahdanau attention softmax.
// B=32, T=64, S=64, U=512, 4U=2048, VOCAB=65.
//
// Round 2: LSTM device barrier rebuilt. Round-1 rocprof: lstm = 673us,
// MfmaUtil 0.25%, VALUBusy 0.9% -> pure sync-bound; the serialized
// fetch_add barrier cost ~10.5us/step (32 serialized LLC RMWs). Replaced
// with per-wg epoch flags: arrival = 1 relaxed agent store to flags[g],
// departure = per-wave coalesced load of all 32 flags + __all() check.
// No RMWs, no shared-line contention.

#define NB 32
#define NT 64
#define NS 64
#define NU 512
#define N4U 2048
#define NV 65
#define NWG 32

typedef unsigned int u32;
typedef __bf16 bf16_t;
typedef bf16_t bf16x8 __attribute__((ext_vector_type(8)));
typedef float f32x4 __attribute__((ext_vector_type(4)));

__device__ __forceinline__ unsigned short f2bf(float f) {
  u32 u = __builtin_bit_cast(u32, f);
  u += 0x7fffu + ((u >> 16) & 1u);   // round-to-nearest-even
  return (unsigned short)(u >> 16);
}
__device__ __forceinline__ float bf2f(unsigned short s) {
  return __builtin_bit_cast(float, (u32)s << 16);
}
__device__ __forceinline__ float sigf(float x) { return 1.0f / (1.0f + __expf(-x)); }
__device__ __forceinline__ float tanhfast(float x) {
  float e = __expf(2.0f * x);
  return 1.0f - 2.0f / (e + 1.0f);   // exact at +-inf, ~1e-6 rel otherwise
}

// ---------------------------------------------------------------------------
// LSTM: grid = 32 wgs x 256 threads (4 waves: wm = batch-half, wn = col-half).
// wg g owns h units [g*16, g*16+16) => its 64 z-columns are
// j = gate*512 + g*16 + u  (gate-local update, no cross-wg gate traffic).
// ---------------------------------------------------------------------------
__global__ __launch_bounds__(256, 1)
void lstm_kernel(const int* __restrict__ labels,
                 const float* __restrict__ h0,
                 const float* __restrict__ c0,
                 const float* __restrict__ Wx,
                 const float* __restrict__ Wh,
                 const float* __restrict__ bias,
                 u32* __restrict__ hbuf,    // [2][32][256] bf16-pairs (LLC-bypass)
                 u32* __restrict__ dec_u,   // [32*64][256] bf16-pairs (plain)
                 u32* __restrict__ flags)   // [32] per-wg epoch (memset 0 per launch)
{
  __shared__ u32   h_lds[NB * 256];   // 32KB, bf16 pairs, XOR-swizzled rows
  __shared__ float z_buf[NB][65];     // padded: conflict-free gate reads
  __shared__ float c_lds[NB][16];
  __shared__ float wx_lds[NV][65];    // Wx slice + bias folded, padded

  const int tid  = threadIdx.x;
  const int g    = blockIdx.x;
  const int wave = tid >> 6, lane = tid & 63;
  const int wm   = wave >> 1, wn = wave & 1;
  const int l15  = lane & 15, l4 = lane >> 4;

  // Wx gather slice (+bias folded): wx_lds[v][c] = Wx[v][gate*512+g*16+u] + b[j]
  for (int i = tid; i < NV * 64; i += 256) {
    int v = i >> 6, c = i & 63;
    int j = (c >> 4) * NU + g * 16 + (c & 15);
    wx_lds[v][c] = Wx[v * N4U + j] + bias[j];
  }
  // c0 slice
  for (int i = tid; i < NB * 16; i += 256) {
    int r = i >> 4, u = i & 15;
    c_lds[r][u] = c0[r * NU + g * 16 + u];
  }
  // h0 -> LDS (bf16, swizzled: uint idx ^= (row&7)<<2  <=> byte ^= (row&7)<<4)
  for (int i = tid; i < NB * 256; i += 256) {
    int r = i >> 8, cu = i & 255;
    u32 pk = (u32)f2bf(h0[r * NU + cu * 2]) | ((u32)f2bf(h0[r * NU + cu * 2 + 1]) << 16);
    h_lds[i ^ ((r & 7) << 2)] = pk;
  }

  // Wh B-fragments -> VGPRs, once. frag(kt,nt): lane holds Wh[k][j],
  // k = kt*32 + (lane>>4)*8 + e, j = col(wn*32 + nt*16 + (lane&15)).
  bf16x8 bfrag[16][2];
#pragma unroll
  for (int kt = 0; kt < 16; ++kt) {
#pragma unroll
    for (int nt = 0; nt < 2; ++nt) {
      int c = wn * 32 + nt * 16 + l15;
      int j = (c >> 4) * NU + g * 16 + (c & 15);
      int kb = kt * 32 + l4 * 8;
      union { unsigned short us[8]; bf16x8 v; } bu;
#pragma unroll
      for (int e = 0; e < 8; ++e) bu.us[e] = f2bf(Wh[(kb + e) * N4U + j]);
      bfrag[kt][nt] = bu.v;
    }
  }

  const int bb = tid >> 3;          // batch handled in update phase
  const int u2 = (tid & 7) * 2;     // unit pair
  const int ci = g * 8 + (tid & 7); // uint col in [32][256] h layout

  for (int s = 0; s < NT; ++s) {
    __syncthreads();  // h_lds ready / z_buf free

    // z = h @ WhSlice
    f32x4 acc0 = {0.f, 0.f, 0.f, 0.f};
    f32x4 acc1 = {0.f, 0.f, 0.f, 0.f};
    const int arow = wm * 16 + l15;
#pragma unroll
    for (int kt = 0; kt < 16; ++kt) {
      int bo = (arow << 10) + (kt << 6) + (l4 << 4);
      bo ^= (arow & 7) << 4;
      bf16x8 a = *reinterpret_cast<const bf16x8*>(
          reinterpret_cast<const char*>(h_lds) + bo);
      acc0 = __builtin_amdgcn_mfma_f32_16x16x32_bf16(a, bfrag[kt][0], acc0, 0, 0, 0);
      acc1 = __builtin_amdgcn_mfma_f32_16x16x32_bf16(a, bfrag[kt][1], acc1, 0, 0, 0);
    }
#pragma unroll
    for (int ri = 0; ri < 4; ++ri) {
      z_buf[wm * 16 + l4 * 4 + ri][wn * 32 + l15]      = acc0[ri];
      z_buf[wm * 16 + l4 * 4 + ri][wn * 32 + 16 + l15] = acc1[ri];
    }
    __syncthreads();

    // gate update (each thread owns (bb, u2..u2+1))
    int lab = labels[bb * NT + s];
    float hv[2];
#pragma unroll
    for (int q = 0; q < 2; ++q) {
      int u = u2 + q;
      float zi = z_buf[bb][u]      + wx_lds[lab][u];
      float zf = z_buf[bb][16 + u] + wx_lds[lab][16 + u];
      float zg = z_buf[bb][32 + u] + wx_lds[lab][32 + u];
      float zo = z_buf[bb][48 + u] + wx_lds[lab][48 + u];
      float cc = sigf(zf) * c_lds[bb][u] + sigf(zi) * tanhfast(zg);
      c_lds[bb][u] = cc;
      hv[q] = sigf(zo) * tanhfast(cc);
    }
    u32 pk = (u32)f2bf(hv[0]) | ((u32)f2bf(hv[1]) << 16);
    dec_u[(bb * NT + s) * 256 + ci] = pk;  // history for attention (plain store)
    if (s == NT - 1) break;                // last h not needed cross-wg
    __hip_atomic_store(hbuf + (((s + 1) & 1) << 13) + bb * 256 + ci, pk,
                       __ATOMIC_RELAXED, __HIP_MEMORY_SCOPE_AGENT);

    // ---- device barrier, per-wg epoch flags (no RMW, no shared line) ----
    // arrive: own h stores confirmed at coherence point, then flags[g]=s+1
    asm volatile("s_waitcnt vmcnt(0)" ::: "memory");  // this wave's stores done
    __syncthreads();                                  // => whole wg's stores done
    if (tid == 0)
      __hip_atomic_store(flags + g, (u32)(s + 1),
                         __ATOMIC_RELAXED, __HIP_MEMORY_SCOPE_AGENT);
    // depart: every wave polls all 32 flags with one coalesced load
    {
      const u32 target = (u32)(s + 1);
      int guard = 0;
      for (;;) {
        u32 f = target;
        if (lane < NWG)
          f = __hip_atomic_load(flags + lane, __ATOMIC_RELAXED,
                                __HIP_MEMORY_SCOPE_AGENT);
        if (__all(f >= target)) break;
        if (++guard > 300000) break;   // anti-hang; break => visible absmax fail
        __builtin_amdgcn_s_sleep(1);
      }
    }

    // reload full h (LLC-bypass loads), re-swizzle into LDS
    const u32* hb = hbuf + (((s + 1) & 1) << 13);
    for (int i = tid; i < NB * 256; i += 256) {
      int r = i >> 8;
      u32 pk2 = __hip_atomic_load(hb + i, __ATOMIC_RELAXED, __HIP_MEMORY_SCOPE_AGENT);
      h_lds[i ^ ((r & 7) << 2)] = pk2;
    }
    // loop-top __syncthreads separates these writes from next MFMA reads
  }
}

// ---------------------------------------------------------------------------
// proj: rows 0..2047 -> d1 = dec@W1+b1 ; rows 2048..4095 -> e2 = enc@W2+b2.
// One wave = 16 rows x 64 cols. grid 512 x 256.
// ---------------------------------------------------------------------------
__global__ __launch_bounds__(256, 1)
void proj_kernel(const u32* __restrict__ dec_u,
                 const float* __restrict__ enc,
                 const float* __restrict__ W1,
                 const float* __restrict__ b1,
                 const float* __restrict__ W2,
                 const float* __restrict__ b2,
                 unsigned short* __restrict__ d1_bf,
                 unsigned short* __restrict__ e2_bf)
{
  const int tid = threadIdx.x;
  const int wave = tid >> 6, lane = tid & 63;
  const int l15 = lane & 15, l4 = lane >> 4;
  const int w  = blockIdx.x * 4 + wave;   // 0..2047
  const int rt = w >> 3, cg = w & 7;
  const bool isdec = (rt < 128);
  const int r0 = (isdec ? rt : rt - 128) * 16;
  const float* Wm  = isdec ? W1 : W2;
  const float* bv_ = isdec ? b1 : b2;
  unsigned short* outp = isdec ? d1_bf : e2_bf;

  f32x4 acc[4] = {};
  const int arow = r0 + l15;
  for (int kt = 0; kt < 16; ++kt) {
    int k0 = kt * 32 + l4 * 8;
    bf16x8 a;
    if (isdec) {
      a = __builtin_bit_cast(bf16x8,
            *reinterpret_cast<const uint4*>(dec_u + arow * 256 + (k0 >> 1)));
    } else {
      const float* ep = enc + arow * NU + k0;
      union { unsigned short us[8]; bf16x8 v; } au;
#pragma unroll
      for (int e = 0; e < 8; ++e) au.us[e] = f2bf(ep[e]);
      a = au.v;
    }
#pragma unroll
    for (int nt = 0; nt < 4; ++nt) {
      int col = cg * 64 + nt * 16 + l15;
      union { unsigned short us[8]; bf16x8 v; } bu;
#pragma unroll
      for (int e = 0; e < 8; ++e) bu.us[e] = f2bf(Wm[(k0 + e) * NU + col]);
      acc[nt] = __builtin_amdgcn_mfma_f32_16x16x32_bf16(a, bu.v, acc[nt], 0, 0, 0);
    }
  }
#pragma unroll
  for (int nt = 0; nt < 4; ++nt) {
    int col = cg * 64 + nt * 16 + l15;
    float bc = bv_[col];
#pragma unroll
    for (int ri = 0; ri < 4; ++ri) {
      int row = r0 + l4 * 4 + ri;
      outp[row * NU + col] = f2bf(acc[nt][ri] + bc);
    }
  }
}

// ---------------------------------------------------------------------------
// score+softmax: one wave per (b,t). lane s holds score[b,t,s]; softmax over
// lanes; store transposed out[b][s][t]. bv is softmax-invariant (dropped).
// grid 512 x 256.
// ---------------------------------------------------------------------------
__global__ __launch_bounds__(256, 1)
void score_kernel(const unsigned short* __restrict__ d1_bf,
                  const unsigned short* __restrict__ e2_bf,
                  const float* __restrict__ V,
                  float* __restrict__ out)
{
  const int tid = threadIdx.x;
  const int wave = tid >> 6, lane = tid & 63;
  const int p = blockIdx.x * 4 + wave;   // 0..2047
  const int bb = p >> 6, t = p & 63;

  union { uint4 q; unsigned short us[8]; } dv;
  dv.q = *reinterpret_cast<const uint4*>(d1_bf + (bb * 64 + t) * NU + lane * 8);
  float d1f[8], Vf[8];
#pragma unroll
  for (int e = 0; e < 8; ++e) { d1f[e] = bf2f(dv.us[e]); Vf[e] = V[lane * 8 + e]; }

  float sc = 0.f;
  for (int s = 0; s < NS; ++s) {
    union { uint4 q; unsigned short us[8]; } ev;
    ev.q = *reinterpret_cast<const uint4*>(e2_bf + (bb * 64 + s) * NU + lane * 8);
    float part = 0.f;
#pragma unroll
    for (int e = 0; e < 8; ++e) part += tanhfast(d1f[e] + bf2f(ev.us[e])) * Vf[e];
#pragma unroll
    for (int o = 32; o > 0; o >>= 1) part += __shfl_xor(part, o);
    sc = (lane == s) ? part : sc;
  }
  float m = sc;
#pragma unroll
  for (int o = 32; o > 0; o >>= 1) m = fmaxf(m, __shfl_xor(m, o));
  float ex = __expf(sc - m);
  float sum = ex;
#pragma unroll
  for (int o = 32; o > 0; o >>= 1) sum += __shfl_xor(sum, o);
  out[(bb * 64 + lane) * 64 + t] = ex / sum;
}

// ---------------------------------------------------------------------------
extern "C" void kernel_launch(void* const* d_in, const int* in_sizes, int n_in,
                              void* d_out, int out_size, void* d_ws, size_t ws_size,
                              hipStream_t stream)
{
  (void)in_sizes; (void)n_in; (void)out_size;
  const int*   labels = (const int*)  d_in[0];
  const float* enc    = (const float*)d_in[1];
  const float* h0     = (const float*)d_in[2];
  const float* c0     = (const float*)d_in[3];
  const float* Wx     = (const float*)d_in[4];
  const float* Wh     = (const float*)d_in[5];
  const float* bias   = (const float*)d_in[6];
  const float* W1     = (const float*)d_in[7];
  const float* b1     = (const float*)d_in[8];
  const float* W2     = (const float*)d_in[9];
  const float* b2     = (const float*)d_in[10];
  const float* V      = (const float*)d_in[11];
  // d_in[12] = bv: additive scalar on all scores -> softmax-invariant.

  char* ws = (char*)d_ws;
  const size_t OFS_HBUF = 1024;                       // 64KB
  const size_t OFS_DEC  = 1u << 17;                   // 2MB
  const size_t OFS_D1   = OFS_DEC + (2u << 20);       // 2MB
  const size_t OFS_E2   = OFS_D1  + (2u << 20);       // 2MB
  if (ws_size < OFS_E2 + (2u << 20)) return;          // ~8.4MB needed

  u32* flags = (u32*)(ws);
  u32* hbuf  = (u32*)(ws + OFS_HBUF);
  u32* dec_u = (u32*)(ws + OFS_DEC);
  unsigned short* d1_bf = (unsigned short*)(ws + OFS_D1);
  unsigned short* e2_bf = (unsigned short*)(ws + OFS_E2);
  float* out = (float*)d_out;

  hipMemsetAsync(flags, 0, 256, stream);
  lstm_kernel<<<dim3(NWG), dim3(256), 0, stream>>>(labels, h0, c0, Wx, Wh, bias,
                                                   hbuf, dec_u, flags);
  proj_kernel<<<dim3(512), dim3(256), 0, stream>>>(dec_u, enc, W1, b1, W2, b2,
                                                   d1_bf, e2_bf);
  score_kernel<<<dim3(512), dim3(256), 0, stream>>>(d1_bf, e2_bf, V, out);
}

// Round 4
// 388.126 us; speedup vs baseline: 1.9317x; 1.9064x over previous
//
#include <hip/hip_runtime.h>
#include <hip/hip_bf16.h>

// Decoder: one-hot@Wx gather -> 64-step LSTM -> Bahdanau attention softmax.
// B=32, T=64, S=64, U=512, 4U=2048, VOCAB=65.
//
// Round 4: r3's NaN = pending inline-asm loads held across the loop
// back-edge (compiler may spill/copy "=v" outputs before the hw write
// lands). Fix: issue all 16 bypass loads AND the s_waitcnt vmcnt(0) inside
// ONE asm block -> outputs valid at asm end, MLP preserved (16 loads, one
// round trip). Tests the reload-serialization theory cleanly:
// r1/r2 = 10.4us/step with 32 serialized agent-atomic loads (~9.6us).

#define NB 32
#define NT 64
#define NS 64
#define NU 512
#define N4U 2048
#define NV 65
#define NWG 32

typedef unsigned int u32;
typedef __bf16 bf16_t;
typedef bf16_t bf16x8 __attribute__((ext_vector_type(8)));
typedef float f32x4 __attribute__((ext_vector_type(4)));
typedef u32 u32x4 __attribute__((ext_vector_type(4)));

__device__ __forceinline__ unsigned short f2bf(float f) {
  u32 u = __builtin_bit_cast(u32, f);
  u += 0x7fffu + ((u >> 16) & 1u);   // round-to-nearest-even
  return (unsigned short)(u >> 16);
}
__device__ __forceinline__ float bf2f(unsigned short s) {
  return __builtin_bit_cast(float, (u32)s << 16);
}
__device__ __forceinline__ u32 pk2(float a, float b) {
  return (u32)f2bf(a) | ((u32)f2bf(b) << 16);
}
__device__ __forceinline__ float sigf(float x) { return 1.0f / (1.0f + __expf(-x)); }
__device__ __forceinline__ float tanhfast(float x) {
  float e = __expf(2.0f * x);
  return 1.0f - 2.0f / (e + 1.0f);
}

// ---------------------------------------------------------------------------
// LSTM: grid = 32 wgs x 256 threads (4 waves: wm = batch-half, wn = col-half).
// wg g owns h units [g*16, g*16+16). Wh slice in VGPRs (bfrag), h in VGPRs
// as MFMA A-fragments (afrag), exchanged via MALL (sc0/sc1) each step.
// ---------------------------------------------------------------------------
__global__ __launch_bounds__(256, 1)
void lstm_kernel(const int* __restrict__ labels,
                 const float* __restrict__ h0,
                 const float* __restrict__ c0,
                 const float* __restrict__ Wx,
                 const float* __restrict__ Wh,
                 const float* __restrict__ bias,
                 u32* __restrict__ hbuf,    // [2][32][256] bf16-pairs
                 u32* __restrict__ dec_u,   // [32*64][256] bf16-pairs
                 u32* __restrict__ flags)   // [32] per-wg epoch (memset 0)
{
  __shared__ float z_buf[NB][65];            // padded: conflict-free gate reads
  __shared__ float c_lds[NB][16];
  __shared__ float wx_lds[NV][65];           // Wx slice + bias folded, padded
  __shared__ unsigned char lab_lds[NB * NT]; // labels cached (values < 65)

  const int tid  = threadIdx.x;
  const int g    = blockIdx.x;
  const int wave = tid >> 6, lane = tid & 63;
  const int wm   = wave >> 1, wn = wave & 1;
  const int l15  = lane & 15, l4 = lane >> 4;

  for (int i = tid; i < NV * 64; i += 256) {
    int v = i >> 6, c = i & 63;
    int j = (c >> 4) * NU + g * 16 + (c & 15);
    wx_lds[v][c] = Wx[v * N4U + j] + bias[j];
  }
  for (int i = tid; i < NB * 16; i += 256) {
    int r = i >> 4, u = i & 15;
    c_lds[r][u] = c0[r * NU + g * 16 + u];
  }
  for (int i = tid; i < NB * NT; i += 256) lab_lds[i] = (unsigned char)labels[i];

  // Wh B-fragments -> VGPRs, once (layout validated r1/r2).
  bf16x8 bfrag[16][2];
#pragma unroll
  for (int kt = 0; kt < 16; ++kt) {
#pragma unroll
    for (int nt = 0; nt < 2; ++nt) {
      int c = wn * 32 + nt * 16 + l15;
      int j = (c >> 4) * NU + g * 16 + (c & 15);
      int kb = kt * 32 + l4 * 8;
      union { unsigned short us[8]; bf16x8 v; } bu;
#pragma unroll
      for (int e = 0; e < 8; ++e) bu.us[e] = f2bf(Wh[(kb + e) * N4U + j]);
      bfrag[kt][nt] = bu.v;
    }
  }

  // A-fragments from h0: lane holds h[arow][kt*32 + l4*8 + e], e=0..7.
  const int arow = wm * 16 + l15;
  u32x4 afrag[16];
#pragma unroll
  for (int kt = 0; kt < 16; ++kt) {
    const float* hp = h0 + arow * NU + kt * 32 + l4 * 8;
    u32x4 t;
    t.x = pk2(hp[0], hp[1]); t.y = pk2(hp[2], hp[3]);
    t.z = pk2(hp[4], hp[5]); t.w = pk2(hp[6], hp[7]);
    afrag[kt] = t;
  }

  const int bb = tid >> 3;          // batch handled in update phase
  const int u2 = (tid & 7) * 2;     // unit pair
  const int ci = g * 8 + (tid & 7); // u32 col in [32][256] h layout

  for (int s = 0; s < NT; ++s) {
    // [B] z = h @ WhSlice  (4 chains; afrag valid: loads waited in-block)
    f32x4 a00 = {0.f,0.f,0.f,0.f}, a01 = a00, a10 = a00, a11 = a00;
#pragma unroll
    for (int kt = 0; kt < 16; kt += 2) {
      bf16x8 av0 = __builtin_bit_cast(bf16x8, afrag[kt]);
      bf16x8 av1 = __builtin_bit_cast(bf16x8, afrag[kt + 1]);
      a00 = __builtin_amdgcn_mfma_f32_16x16x32_bf16(av0, bfrag[kt][0],     a00, 0, 0, 0);
      a10 = __builtin_amdgcn_mfma_f32_16x16x32_bf16(av0, bfrag[kt][1],     a10, 0, 0, 0);
      a01 = __builtin_amdgcn_mfma_f32_16x16x32_bf16(av1, bfrag[kt + 1][0], a01, 0, 0, 0);
      a11 = __builtin_amdgcn_mfma_f32_16x16x32_bf16(av1, bfrag[kt + 1][1], a11, 0, 0, 0);
    }
    f32x4 acc0 = a00 + a01, acc1 = a10 + a11;

    // [C] z -> LDS
#pragma unroll
    for (int ri = 0; ri < 4; ++ri) {
      z_buf[wm * 16 + l4 * 4 + ri][wn * 32 + l15]      = acc0[ri];
      z_buf[wm * 16 + l4 * 4 + ri][wn * 32 + 16 + l15] = acc1[ri];
    }
    __syncthreads();  // [D]

    // [E] gate update (thread owns (bb, u2..u2+1))
    int lab = lab_lds[bb * NT + s];
    float hv[2];
#pragma unroll
    for (int q = 0; q < 2; ++q) {
      int u = u2 + q;
      float zi = z_buf[bb][u]      + wx_lds[lab][u];
      float zf = z_buf[bb][16 + u] + wx_lds[lab][16 + u];
      float zg = z_buf[bb][32 + u] + wx_lds[lab][32 + u];
      float zo = z_buf[bb][48 + u] + wx_lds[lab][48 + u];
      float cc = sigf(zf) * c_lds[bb][u] + sigf(zi) * tanhfast(zg);
      c_lds[bb][u] = cc;
      hv[q] = sigf(zo) * tanhfast(cc);
    }
    u32 pkv = pk2(hv[0], hv[1]);

    if (s == NT - 1) {                          // last h: history only
      dec_u[(bb * NT + s) * 256 + ci] = pkv;
      break;
    }

    // [F] publish own slice (agent scope, relaxed)
    __hip_atomic_store(hbuf + (((s + 1) & 1) << 13) + bb * 256 + ci, pkv,
                       __ATOMIC_RELAXED, __HIP_MEMORY_SCOPE_AGENT);

    // [G] own stores acked at coherence point, whole wg done
    asm volatile("s_waitcnt vmcnt(0)" ::: "memory");
    __syncthreads();   // also fences z_buf read (E) vs next write (C)

    // [H] arrive
    if (tid == 0)
      __hip_atomic_store(flags + g, (u32)(s + 1),
                         __ATOMIC_RELAXED, __HIP_MEMORY_SCOPE_AGENT);

    // [I] history store, off the fence path
    dec_u[(bb * NT + s) * 256 + ci] = pkv;

    // [J] depart: poll all 32 flags, one coalesced load per wave
    {
      const u32 target = (u32)(s + 1);
      int guard = 0;
      for (;;) {
        u32 f = target;
        if (lane < NWG)
          f = __hip_atomic_load(flags + lane, __ATOMIC_RELAXED,
                                __HIP_MEMORY_SCOPE_AGENT);
        if (__all(f >= target)) break;
        if (++guard > 300000) break;   // anti-hang; break => visible absmax fail
        __builtin_amdgcn_s_sleep(1);
      }
    }

    // [K] 16 independent bypass loads -> next A-fragments, waited IN-BLOCK.
    // lane reads hbuf_p[arow][kt*16 + l4*4 .. +4) u32 = units kt*32+l4*8..+8.
    {
      const u32* ap = hbuf + (((s + 1) & 1) << 13) + arow * 256 + l4 * 4;
      asm volatile(
        "global_load_dwordx4 %0, %16, off sc0 sc1\n\t"
        "global_load_dwordx4 %1, %16, off offset:64 sc0 sc1\n\t"
        "global_load_dwordx4 %2, %16, off offset:128 sc0 sc1\n\t"
        "global_load_dwordx4 %3, %16, off offset:192 sc0 sc1\n\t"
        "global_load_dwordx4 %4, %16, off offset:256 sc0 sc1\n\t"
        "global_load_dwordx4 %5, %16, off offset:320 sc0 sc1\n\t"
        "global_load_dwordx4 %6, %16, off offset:384 sc0 sc1\n\t"
        "global_load_dwordx4 %7, %16, off offset:448 sc0 sc1\n\t"
        "global_load_dwordx4 %8, %16, off offset:512 sc0 sc1\n\t"
        "global_load_dwordx4 %9, %16, off offset:576 sc0 sc1\n\t"
        "global_load_dwordx4 %10, %16, off offset:640 sc0 sc1\n\t"
        "global_load_dwordx4 %11, %16, off offset:704 sc0 sc1\n\t"
        "global_load_dwordx4 %12, %16, off offset:768 sc0 sc1\n\t"
        "global_load_dwordx4 %13, %16, off offset:832 sc0 sc1\n\t"
        "global_load_dwordx4 %14, %16, off offset:896 sc0 sc1\n\t"
        "global_load_dwordx4 %15, %16, off offset:960 sc0 sc1\n\t"
        "s_waitcnt vmcnt(0)"
        : "=&v"(afrag[0]),  "=&v"(afrag[1]),  "=&v"(afrag[2]),  "=&v"(afrag[3]),
          "=&v"(afrag[4]),  "=&v"(afrag[5]),  "=&v"(afrag[6]),  "=&v"(afrag[7]),
          "=&v"(afrag[8]),  "=&v"(afrag[9]),  "=&v"(afrag[10]), "=&v"(afrag[11]),
          "=&v"(afrag[12]), "=&v"(afrag[13]), "=&v"(afrag[14]), "=&v"(afrag[15])
        : "v"(ap)
        : "memory");
    }
  }
}

// ---------------------------------------------------------------------------
// proj: rows 0..2047 -> d1 = dec@W1+b1 ; rows 2048..4095 -> e2 = enc@W2+b2.
// ---------------------------------------------------------------------------
__global__ __launch_bounds__(256, 1)
void proj_kernel(const u32* __restrict__ dec_u,
                 const float* __restrict__ enc,
                 const float* __restrict__ W1,
                 const float* __restrict__ b1,
                 const float* __restrict__ W2,
                 const float* __restrict__ b2,
                 unsigned short* __restrict__ d1_bf,
                 unsigned short* __restrict__ e2_bf)
{
  const int tid = threadIdx.x;
  const int wave = tid >> 6, lane = tid & 63;
  const int l15 = lane & 15, l4 = lane >> 4;
  const int w  = blockIdx.x * 4 + wave;   // 0..2047
  const int rt = w >> 3, cg = w & 7;
  const bool isdec = (rt < 128);
  const int r0 = (isdec ? rt : rt - 128) * 16;
  const float* Wm  = isdec ? W1 : W2;
  const float* bv_ = isdec ? b1 : b2;
  unsigned short* outp = isdec ? d1_bf : e2_bf;

  f32x4 acc[4] = {};
  const int arow = r0 + l15;
  for (int kt = 0; kt < 16; ++kt) {
    int k0 = kt * 32 + l4 * 8;
    bf16x8 a;
    if (isdec) {
      a = __builtin_bit_cast(bf16x8,
            *reinterpret_cast<const uint4*>(dec_u + arow * 256 + (k0 >> 1)));
    } else {
      const float* ep = enc + arow * NU + k0;
      union { unsigned short us[8]; bf16x8 v; } au;
#pragma unroll
      for (int e = 0; e < 8; ++e) au.us[e] = f2bf(ep[e]);
      a = au.v;
    }
#pragma unroll
    for (int nt = 0; nt < 4; ++nt) {
      int col = cg * 64 + nt * 16 + l15;
      union { unsigned short us[8]; bf16x8 v; } bu;
#pragma unroll
      for (int e = 0; e < 8; ++e) bu.us[e] = f2bf(Wm[(k0 + e) * NU + col]);
      acc[nt] = __builtin_amdgcn_mfma_f32_16x16x32_bf16(a, bu.v, acc[nt], 0, 0, 0);
    }
  }
#pragma unroll
  for (int nt = 0; nt < 4; ++nt) {
    int col = cg * 64 + nt * 16 + l15;
    float bc = bv_[col];
#pragma unroll
    for (int ri = 0; ri < 4; ++ri) {
      int row = r0 + l4 * 4 + ri;
      outp[row * NU + col] = f2bf(acc[nt][ri] + bc);
    }
  }
}

// ---------------------------------------------------------------------------
// score+softmax: one wave per (b,t); softmax over lanes; store out[b][s][t].
// ---------------------------------------------------------------------------
__global__ __launch_bounds__(256, 1)
void score_kernel(const unsigned short* __restrict__ d1_bf,
                  const unsigned short* __restrict__ e2_bf,
                  const float* __restrict__ V,
                  float* __restrict__ out)
{
  const int tid = threadIdx.x;
  const int wave = tid >> 6, lane = tid & 63;
  const int p = blockIdx.x * 4 + wave;   // 0..2047
  const int bb = p >> 6, t = p & 63;

  union { uint4 q; unsigned short us[8]; } dv;
  dv.q = *reinterpret_cast<const uint4*>(d1_bf + (bb * 64 + t) * NU + lane * 8);
  float d1f[8], Vf[8];
#pragma unroll
  for (int e = 0; e < 8; ++e) { d1f[e] = bf2f(dv.us[e]); Vf[e] = V[lane * 8 + e]; }

  float sc = 0.f;
  for (int s = 0; s < NS; ++s) {
    union { uint4 q; unsigned short us[8]; } ev;
    ev.q = *reinterpret_cast<const uint4*>(e2_bf + (bb * 64 + s) * NU + lane * 8);
    float part = 0.f;
#pragma unroll
    for (int e = 0; e < 8; ++e) part += tanhfast(d1f[e] + bf2f(ev.us[e])) * Vf[e];
#pragma unroll
    for (int o = 32; o > 0; o >>= 1) part += __shfl_xor(part, o);
    sc = (lane == s) ? part : sc;
  }
  float m = sc;
#pragma unroll
  for (int o = 32; o > 0; o >>= 1) m = fmaxf(m, __shfl_xor(m, o));
  float ex = __expf(sc - m);
  float sum = ex;
#pragma unroll
  for (int o = 32; o > 0; o >>= 1) sum += __shfl_xor(sum, o);
  out[(bb * 64 + lane) * 64 + t] = ex / sum;
}

// ---------------------------------------------------------------------------
extern "C" void kernel_launch(void* const* d_in, const int* in_sizes, int n_in,
                              void* d_out, int out_size, void* d_ws, size_t ws_size,
                              hipStream_t stream)
{
  (void)in_sizes; (void)n_in; (void)out_size;
  const int*   labels = (const int*)  d_in[0];
  const float* enc    = (const float*)d_in[1];
  const float* h0     = (const float*)d_in[2];
  const float* c0     = (const float*)d_in[3];
  const float* Wx     = (const float*)d_in[4];
  const float* Wh     = (const float*)d_in[5];
  const float* bias   = (const float*)d_in[6];
  const float* W1     = (const float*)d_in[7];
  const float* b1     = (const float*)d_in[8];
  const float* W2     = (const float*)d_in[9];
  const float* b2     = (const float*)d_in[10];
  const float* V      = (const float*)d_in[11];
  // d_in[12] = bv: additive scalar on all scores -> softmax-invariant.

  char* ws = (char*)d_ws;
  const size_t OFS_HBUF = 1024;                       // 64KB
  const size_t OFS_DEC  = 1u << 17;                   // 2MB
  const size_t OFS_D1   = OFS_DEC + (2u << 20);       // 2MB
  const size_t OFS_E2   = OFS_D1  + (2u << 20);       // 2MB
  if (ws_size < OFS_E2 + (2u << 20)) return;          // ~8.4MB needed

  u32* flags = (u32*)(ws);
  u32* hbuf  = (u32*)(ws + OFS_HBUF);
  u32* dec_u = (u32*)(ws + OFS_DEC);
  unsigned short* d1_bf = (unsigned short*)(ws + OFS_D1);
  unsigned short* e2_bf = (unsigned short*)(ws + OFS_E2);
  float* out = (float*)d_out;

  hipMemsetAsync(flags, 0, 256, stream);
  lstm_kernel<<<dim3(NWG), dim3(256), 0, stream>>>(labels, h0, c0, Wx, Wh, bias,
                                                   hbuf, dec_u, flags);
  proj_kernel<<<dim3(512), dim3(256), 0, stream>>>(dec_u, enc, W1, b1, W2, b2,
                                                   d1_bf, e2_bf);
  score_kernel<<<dim3(512), dim3(256), 0, stream>>>(d1_bf, e2_bf, V, out);
}